// Round 3
// baseline (35247.723 us; speedup 1.0000x reference)
//
#include <hip/hip_runtime.h>
#include <math.h>

#define TT 2048
#define II 128
#define NN 1024
#define NWG 256        // 64 i-blocks x 4 j-groups
#define NTHR 512

// Thread mapping (512 = 32 ksplit x 4 rowgroups x 4 batchpairs):
//   ks = tid[0:4]  : k-split lane, owns k in [ks*32, ks*32+32)
//   rt = tid[5:6]  : row group, owns rows ig*16 + rt*4 + {0..3}
//   bt = tid[7:8]  : batch pair, owns batches jg*8 + bt*2 + {0,1}
// Each thread: 4 rows x 2 batches x 32 k -> 256 FMA per 256 LDS bytes (ratio 1.0)

__global__ __launch_bounds__(NTHR) void esn_kernel(
    const float* __restrict__ u, const float* __restrict__ w_in,
    const float* __restrict__ w, const float* __restrict__ w_bias,
    float* __restrict__ out, unsigned int* __restrict__ flags)
{
    // h staged per step, XOR-swizzled: word = bl*1024 + (k ^ ((k>>5 & 7)<<2))
    __shared__ alignas(16) float h_stage[8 * 1024];  // 32 KB

    const int tid = threadIdx.x;
    const int wg  = blockIdx.x;
    const int ig  = wg & 63;
    const int jg  = wg >> 6;
    const int ks  = tid & 31;
    const int rt  = (tid >> 5) & 3;
    const int bt  = (tid >> 7) & 3;
    const int lane = tid & 63;

    // ---- persistent register state ----
    float4 wreg[4][8];   // W[4 rows][k-chunk 32] = 128 VGPR
    float4 wir[4];       // W_in[4 rows][ks*4 .. +4)
    float  bias[4];
    #pragma unroll
    for (int rr = 0; rr < 4; ++rr) {
        const int n = ig * 16 + rt * 4 + rr;
        const float* wrow = w + (size_t)n * NN + ks * 32;
        #pragma unroll
        for (int q = 0; q < 8; ++q)
            wreg[rr][q] = reinterpret_cast<const float4*>(wrow)[q];
        wir[rr]  = *reinterpret_cast<const float4*>(w_in + n * II + ks * 4);
        bias[rr] = w_bias[n];
    }

    const int bg0 = jg * 8 + bt * 2;
    const int bg1 = bg0 + 1;
    const int n0  = ig * 16 + rt * 4;

    // walking pointers (incremented per step)
    const float* ua0 = u + ((size_t)bg0 * TT) * II + ks * 4;
    const float* ua1 = u + ((size_t)bg1 * TT) * II + ks * 4;
    float* ob0 = out + ((size_t)bg0 * TT) * NN + n0;
    float* ob1 = out + ((size_t)bg1 * TT) * NN + n0;
    // h staging sources: 4 chunks/thread; init for t-1 = 0 minus one step (inc at loop end)
    const float* hp[4];
    int hw[4];  // swizzled LDS word per chunk
    #pragma unroll
    for (int c = 0; c < 4; ++c) {
        int f4 = c * NTHR + tid;       // 0..2047
        int bl = f4 >> 8;              // batch-local 0..7
        int k4 = f4 & 255;             // float4 index in row
        hp[c] = out + ((size_t)(jg * 8 + bl) * TT) * NN + k4 * 4 - NN;
        hw[c] = bl * 1024 + ((k4 * 4) ^ (((k4 >> 3) & 7) << 2));
    }
    // main-loop LDS read bases (swizzle applied per-q)
    const int swz    = (ks & 7) << 2;
    const int base0  = (bt * 2 + 0) * 1024 + ks * 32;
    const int base1  = (bt * 2 + 1) * 1024 + ks * 32;

    unsigned int* gflags = flags + jg * 64;

    for (int t = 0; t < TT; ++t) {
        // -- issue u loads (overlap the poll) --
        float4 u0, u1;
        asm volatile("global_load_dwordx4 %0, %1, off" : "=v"(u0) : "v"(ua0));
        asm volatile("global_load_dwordx4 %0, %1, off" : "=v"(u1) : "v"(ua1));

        float4 h0, h1, h2, h3;
        if (t > 0) {
            for (;;) {
                unsigned int v = __hip_atomic_load(&gflags[lane], __ATOMIC_RELAXED,
                                                   __HIP_MEMORY_SCOPE_AGENT);
                if (__all((int)(v >= (unsigned)t))) break;
                __builtin_amdgcn_s_sleep(1);
            }
            asm volatile("" ::: "memory");
            // h_{t-1} -> regs, IC-coherent (sc1), 4x dwordx4 per thread
            asm volatile("global_load_dwordx4 %0, %1, off sc1" : "=v"(h0) : "v"(hp[0]));
            asm volatile("global_load_dwordx4 %0, %1, off sc1" : "=v"(h1) : "v"(hp[1]));
            asm volatile("global_load_dwordx4 %0, %1, off sc1" : "=v"(h2) : "v"(hp[2]));
            asm volatile("global_load_dwordx4 %0, %1, off sc1" : "=v"(h3) : "v"(hp[3]));
            asm volatile("s_waitcnt vmcnt(4)" ::: "memory");  // u retired, h in flight
            __builtin_amdgcn_sched_barrier(0);
        } else {
            asm volatile("s_waitcnt vmcnt(0)" ::: "memory");
            __builtin_amdgcn_sched_barrier(0);
        }

        // -- W_in . u partial (hides h load latency) --
        float acc00 = wir[0].x*u0.x + wir[0].y*u0.y + wir[0].z*u0.z + wir[0].w*u0.w;
        float acc10 = wir[1].x*u0.x + wir[1].y*u0.y + wir[1].z*u0.z + wir[1].w*u0.w;
        float acc20 = wir[2].x*u0.x + wir[2].y*u0.y + wir[2].z*u0.z + wir[2].w*u0.w;
        float acc30 = wir[3].x*u0.x + wir[3].y*u0.y + wir[3].z*u0.z + wir[3].w*u0.w;
        float acc01 = wir[0].x*u1.x + wir[0].y*u1.y + wir[0].z*u1.z + wir[0].w*u1.w;
        float acc11 = wir[1].x*u1.x + wir[1].y*u1.y + wir[1].z*u1.z + wir[1].w*u1.w;
        float acc21 = wir[2].x*u1.x + wir[2].y*u1.y + wir[2].z*u1.z + wir[2].w*u1.w;
        float acc31 = wir[3].x*u1.x + wir[3].y*u1.y + wir[3].z*u1.z + wir[3].w*u1.w;

        if (t > 0) {
            asm volatile("s_waitcnt vmcnt(0)" ::: "memory");  // h regs ready
            __builtin_amdgcn_sched_barrier(0);
        }
        __syncthreads();            // S1a: prev-step LDS readers done (end-of-step
                                    // barrier of t-1 already guarantees; this one
                                    // orders ds_write visibility below)
        if (t > 0) {
            *reinterpret_cast<float4*>(&h_stage[hw[0]]) = h0;
            *reinterpret_cast<float4*>(&h_stage[hw[1]]) = h1;
            *reinterpret_cast<float4*>(&h_stage[hw[2]]) = h2;
            *reinterpret_cast<float4*>(&h_stage[hw[3]]) = h3;
        }
        __syncthreads();            // S1b: h_stage visible to all

        // -- main W . h loop: 16 ds_read_b128 + 256 FMA per thread --
        if (t > 0) {
            #pragma unroll
            for (int q = 0; q < 8; ++q) {
                const int o = (q * 4) ^ swz;
                float4 hv0 = *reinterpret_cast<const float4*>(&h_stage[base0 + o]);
                float4 hv1 = *reinterpret_cast<const float4*>(&h_stage[base1 + o]);
                float4 w0 = wreg[0][q], w1 = wreg[1][q], w2 = wreg[2][q], w3 = wreg[3][q];
                acc00 += w0.x*hv0.x + w0.y*hv0.y + w0.z*hv0.z + w0.w*hv0.w;
                acc10 += w1.x*hv0.x + w1.y*hv0.y + w1.z*hv0.z + w1.w*hv0.w;
                acc20 += w2.x*hv0.x + w2.y*hv0.y + w2.z*hv0.z + w2.w*hv0.w;
                acc30 += w3.x*hv0.x + w3.y*hv0.y + w3.z*hv0.z + w3.w*hv0.w;
                acc01 += w0.x*hv1.x + w0.y*hv1.y + w0.z*hv1.z + w0.w*hv1.w;
                acc11 += w1.x*hv1.x + w1.y*hv1.y + w1.z*hv1.z + w1.w*hv1.w;
                acc21 += w2.x*hv1.x + w2.y*hv1.y + w2.z*hv1.z + w2.w*hv1.w;
                acc31 += w3.x*hv1.x + w3.y*hv1.y + w3.z*hv1.z + w3.w*hv1.w;
            }
        }

        // -- reduce over 32 k-split lanes (bits 0..4) --
        float red[8] = {acc00, acc10, acc20, acc30, acc01, acc11, acc21, acc31};
        #pragma unroll
        for (int i = 0; i < 8; ++i) {
            float a = red[i];
            a += __shfl_xor(a, 1);
            a += __shfl_xor(a, 2);
            a += __shfl_xor(a, 4);
            a += __shfl_xor(a, 8);
            a += __shfl_xor(a, 16);
            red[i] = a;
        }

        if (ks == 0) {
            #pragma unroll
            for (int rr = 0; rr < 4; ++rr) {
                float hv0 = tanhf(red[rr]     + bias[rr]);
                float hv1 = tanhf(red[4 + rr] + bias[rr]);
                __hip_atomic_store(ob0 + (size_t)t * NN + rr, hv0,
                                   __ATOMIC_RELAXED, __HIP_MEMORY_SCOPE_AGENT);
                __hip_atomic_store(ob1 + (size_t)t * NN + rr, hv1,
                                   __ATOMIC_RELAXED, __HIP_MEMORY_SCOPE_AGENT);
            }
        }

        asm volatile("s_waitcnt vmcnt(0)" ::: "memory");  // all h_t stores durable
        __syncthreads();                                  // S2: whole WG drained
        if (tid == 0) {
            __hip_atomic_store(&gflags[ig], (unsigned)(t + 1),
                               __ATOMIC_RELAXED, __HIP_MEMORY_SCOPE_AGENT);
        }

        // advance walking pointers
        ua0 += II; ua1 += II;
        #pragma unroll
        for (int c = 0; c < 4; ++c) hp[c] += NN;
    }
}

extern "C" void kernel_launch(void* const* d_in, const int* in_sizes, int n_in,
                              void* d_out, int out_size, void* d_ws, size_t ws_size,
                              hipStream_t stream) {
    const float* u      = (const float*)d_in[0];
    const float* w_in   = (const float*)d_in[1];
    const float* w      = (const float*)d_in[2];
    const float* w_bias = (const float*)d_in[3];
    float* out          = (float*)d_out;
    unsigned int* flags = (unsigned int*)d_ws;

    hipMemsetAsync(flags, 0, 4 * 64 * sizeof(unsigned int), stream);

    // 256 WGs x 512 threads = exactly 1 WG per CU -> co-residency guaranteed,
    // flag spin cannot deadlock.
    esn_kernel<<<dim3(NWG), dim3(NTHR), 0, stream>>>(u, w_in, w, w_bias, out, flags);
}

// Round 4
// 35191.064 us; speedup vs baseline: 1.0016x; 1.0016x over previous
//
#include <hip/hip_runtime.h>
#include <math.h>

#define TT 2048
#define II 128
#define NN 1024
#define NWG 256        // 64 i-blocks x 4 j-groups
#define NTHR 512

// Thread mapping (512 = 32 ksplit x 4 rowgroups x 4 batchpairs):
//   ks = tid[0:4]  : k-split lane, owns k in [ks*32, ks*32+32)
//   rt = tid[5:6]  : row group, owns rows ig*16 + rt*4 + {0..3}
//   bt = tid[7:8]  : batch pair, owns batches jg*8 + bt*2 + {0,1}
// Each thread: 4 rows x 2 batches x 32 k -> 256 FMA per 256 LDS bytes (ratio 1.0)
//
// __launch_bounds__(512, 2): 2 waves/SIMD -> VGPR cap 256. Demand ~220 (wreg=128
// + wir/bias/acc/h/u/addr). R3 shipped without this and the compiler capped at
// 128 VGPR -> ~80 regs spilled to scratch -> 45 GB of HBM spill traffic.

__global__ __launch_bounds__(NTHR, 2) void esn_kernel(
    const float* __restrict__ u, const float* __restrict__ w_in,
    const float* __restrict__ w, const float* __restrict__ w_bias,
    float* __restrict__ out, unsigned int* __restrict__ flags)
{
    // h staged per step, XOR-swizzled: word = bl*1024 + (k ^ ((k>>5 & 7)<<2))
    __shared__ alignas(16) float h_stage[8 * 1024];  // 32 KB

    const int tid = threadIdx.x;
    const int wg  = blockIdx.x;
    const int ig  = wg & 63;
    const int jg  = wg >> 6;
    const int ks  = tid & 31;
    const int rt  = (tid >> 5) & 3;
    const int bt  = (tid >> 7) & 3;
    const int lane = tid & 63;

    // ---- persistent register state ----
    float4 wreg[4][8];   // W[4 rows][k-chunk 32] = 128 VGPR
    float4 wir[4];       // W_in[4 rows][ks*4 .. +4)
    float  bias[4];
    #pragma unroll
    for (int rr = 0; rr < 4; ++rr) {
        const int n = ig * 16 + rt * 4 + rr;
        const float* wrow = w + (size_t)n * NN + ks * 32;
        #pragma unroll
        for (int q = 0; q < 8; ++q)
            wreg[rr][q] = reinterpret_cast<const float4*>(wrow)[q];
        wir[rr]  = *reinterpret_cast<const float4*>(w_in + n * II + ks * 4);
        bias[rr] = w_bias[n];
    }

    const int bg0 = jg * 8 + bt * 2;
    const int bg1 = bg0 + 1;
    const int n0  = ig * 16 + rt * 4;

    // walking pointers (incremented per step)
    const float* ua0 = u + ((size_t)bg0 * TT) * II + ks * 4;
    const float* ua1 = u + ((size_t)bg1 * TT) * II + ks * 4;
    float* ob0 = out + ((size_t)bg0 * TT) * NN + n0;
    float* ob1 = out + ((size_t)bg1 * TT) * NN + n0;
    // h staging sources: 4 chunks/thread; init for t-1 = 0 minus one step (inc at loop end)
    const float* hp[4];
    int hw[4];  // swizzled LDS word per chunk
    #pragma unroll
    for (int c = 0; c < 4; ++c) {
        int f4 = c * NTHR + tid;       // 0..2047
        int bl = f4 >> 8;              // batch-local 0..7
        int k4 = f4 & 255;             // float4 index in row
        hp[c] = out + ((size_t)(jg * 8 + bl) * TT) * NN + k4 * 4 - NN;
        hw[c] = bl * 1024 + ((k4 * 4) ^ (((k4 >> 3) & 7) << 2));
    }
    // main-loop LDS read bases (swizzle applied per-q)
    const int swz    = (ks & 7) << 2;
    const int base0  = (bt * 2 + 0) * 1024 + ks * 32;
    const int base1  = (bt * 2 + 1) * 1024 + ks * 32;

    unsigned int* gflags = flags + jg * 64;

    for (int t = 0; t < TT; ++t) {
        // -- issue u loads (overlap the poll) --
        float4 u0, u1;
        asm volatile("global_load_dwordx4 %0, %1, off" : "=v"(u0) : "v"(ua0));
        asm volatile("global_load_dwordx4 %0, %1, off" : "=v"(u1) : "v"(ua1));

        float4 h0, h1, h2, h3;
        if (t > 0) {
            for (;;) {
                unsigned int v = __hip_atomic_load(&gflags[lane], __ATOMIC_RELAXED,
                                                   __HIP_MEMORY_SCOPE_AGENT);
                if (__all((int)(v >= (unsigned)t))) break;
                __builtin_amdgcn_s_sleep(1);
            }
            asm volatile("" ::: "memory");
            // h_{t-1} -> regs, IC-coherent (sc1), 4x dwordx4 per thread
            asm volatile("global_load_dwordx4 %0, %1, off sc1" : "=v"(h0) : "v"(hp[0]));
            asm volatile("global_load_dwordx4 %0, %1, off sc1" : "=v"(h1) : "v"(hp[1]));
            asm volatile("global_load_dwordx4 %0, %1, off sc1" : "=v"(h2) : "v"(hp[2]));
            asm volatile("global_load_dwordx4 %0, %1, off sc1" : "=v"(h3) : "v"(hp[3]));
            asm volatile("s_waitcnt vmcnt(4)" ::: "memory");  // u retired, h in flight
            __builtin_amdgcn_sched_barrier(0);
        } else {
            asm volatile("s_waitcnt vmcnt(0)" ::: "memory");
            __builtin_amdgcn_sched_barrier(0);
        }

        // -- W_in . u partial (hides h load latency) --
        float acc00 = wir[0].x*u0.x + wir[0].y*u0.y + wir[0].z*u0.z + wir[0].w*u0.w;
        float acc10 = wir[1].x*u0.x + wir[1].y*u0.y + wir[1].z*u0.z + wir[1].w*u0.w;
        float acc20 = wir[2].x*u0.x + wir[2].y*u0.y + wir[2].z*u0.z + wir[2].w*u0.w;
        float acc30 = wir[3].x*u0.x + wir[3].y*u0.y + wir[3].z*u0.z + wir[3].w*u0.w;
        float acc01 = wir[0].x*u1.x + wir[0].y*u1.y + wir[0].z*u1.z + wir[0].w*u1.w;
        float acc11 = wir[1].x*u1.x + wir[1].y*u1.y + wir[1].z*u1.z + wir[1].w*u1.w;
        float acc21 = wir[2].x*u1.x + wir[2].y*u1.y + wir[2].z*u1.z + wir[2].w*u1.w;
        float acc31 = wir[3].x*u1.x + wir[3].y*u1.y + wir[3].z*u1.z + wir[3].w*u1.w;

        if (t > 0) {
            asm volatile("s_waitcnt vmcnt(0)" ::: "memory");  // h regs ready
            __builtin_amdgcn_sched_barrier(0);
        }
        __syncthreads();            // S1a: orders h_stage writes vs prior-step reads
        if (t > 0) {
            *reinterpret_cast<float4*>(&h_stage[hw[0]]) = h0;
            *reinterpret_cast<float4*>(&h_stage[hw[1]]) = h1;
            *reinterpret_cast<float4*>(&h_stage[hw[2]]) = h2;
            *reinterpret_cast<float4*>(&h_stage[hw[3]]) = h3;
        }
        __syncthreads();            // S1b: h_stage visible to all

        // -- main W . h loop: 16 ds_read_b128 + 256 FMA per thread --
        if (t > 0) {
            #pragma unroll
            for (int q = 0; q < 8; ++q) {
                const int o = (q * 4) ^ swz;
                float4 hv0 = *reinterpret_cast<const float4*>(&h_stage[base0 + o]);
                float4 hv1 = *reinterpret_cast<const float4*>(&h_stage[base1 + o]);
                float4 w0 = wreg[0][q], w1 = wreg[1][q], w2 = wreg[2][q], w3 = wreg[3][q];
                acc00 += w0.x*hv0.x + w0.y*hv0.y + w0.z*hv0.z + w0.w*hv0.w;
                acc10 += w1.x*hv0.x + w1.y*hv0.y + w1.z*hv0.z + w1.w*hv0.w;
                acc20 += w2.x*hv0.x + w2.y*hv0.y + w2.z*hv0.z + w2.w*hv0.w;
                acc30 += w3.x*hv0.x + w3.y*hv0.y + w3.z*hv0.z + w3.w*hv0.w;
                acc01 += w0.x*hv1.x + w0.y*hv1.y + w0.z*hv1.z + w0.w*hv1.w;
                acc11 += w1.x*hv1.x + w1.y*hv1.y + w1.z*hv1.z + w1.w*hv1.w;
                acc21 += w2.x*hv1.x + w2.y*hv1.y + w2.z*hv1.z + w2.w*hv1.w;
                acc31 += w3.x*hv1.x + w3.y*hv1.y + w3.z*hv1.z + w3.w*hv1.w;
            }
        }

        // -- reduce over 32 k-split lanes (bits 0..4) --
        float red[8] = {acc00, acc10, acc20, acc30, acc01, acc11, acc21, acc31};
        #pragma unroll
        for (int i = 0; i < 8; ++i) {
            float a = red[i];
            a += __shfl_xor(a, 1);
            a += __shfl_xor(a, 2);
            a += __shfl_xor(a, 4);
            a += __shfl_xor(a, 8);
            a += __shfl_xor(a, 16);
            red[i] = a;
        }

        if (ks == 0) {
            #pragma unroll
            for (int rr = 0; rr < 4; ++rr) {
                float hv0 = tanhf(red[rr]     + bias[rr]);
                float hv1 = tanhf(red[4 + rr] + bias[rr]);
                __hip_atomic_store(ob0 + (size_t)t * NN + rr, hv0,
                                   __ATOMIC_RELAXED, __HIP_MEMORY_SCOPE_AGENT);
                __hip_atomic_store(ob1 + (size_t)t * NN + rr, hv1,
                                   __ATOMIC_RELAXED, __HIP_MEMORY_SCOPE_AGENT);
            }
        }

        asm volatile("s_waitcnt vmcnt(0)" ::: "memory");  // all h_t stores durable
        __syncthreads();                                  // S2: whole WG drained
        if (tid == 0) {
            __hip_atomic_store(&gflags[ig], (unsigned)(t + 1),
                               __ATOMIC_RELAXED, __HIP_MEMORY_SCOPE_AGENT);
        }

        // advance walking pointers
        ua0 += II; ua1 += II;
        #pragma unroll
        for (int c = 0; c < 4; ++c) hp[c] += NN;
    }
}

extern "C" void kernel_launch(void* const* d_in, const int* in_sizes, int n_in,
                              void* d_out, int out_size, void* d_ws, size_t ws_size,
                              hipStream_t stream) {
    const float* u      = (const float*)d_in[0];
    const float* w_in   = (const float*)d_in[1];
    const float* w      = (const float*)d_in[2];
    const float* w_bias = (const float*)d_in[3];
    float* out          = (float*)d_out;
    unsigned int* flags = (unsigned int*)d_ws;

    hipMemsetAsync(flags, 0, 4 * 64 * sizeof(unsigned int), stream);

    // 256 WGs x 512 threads = exactly 1 WG per CU -> co-residency guaranteed,
    // flag spin cannot deadlock.
    esn_kernel<<<dim3(NWG), dim3(NTHR), 0, stream>>>(u, w_in, w, w_bias, out, flags);
}